// Round 2
// baseline (98.810 us; speedup 1.0000x reference)
//
#include <hip/hip_runtime.h>

#define N_CAND 8192
#define TILE 256

__global__ __launch_bounds__(TILE) void ranknet_loss_kernel(
    const float* __restrict__ logits,
    const int*   __restrict__ rankings,
    float*       __restrict__ out)
{
    const int bi = blockIdx.x;   // i-tile index
    const int bj = blockIdx.y;   // j-tile index
    if (bi > bj) return;         // strictly-below-diagonal tiles contribute nothing

    __shared__ float s_lj[TILE];
    __shared__ float s_rj[TILE];
    __shared__ float s_partial[TILE / 64];

    const int tid = threadIdx.x;
    const int i  = bi * TILE + tid;
    const float li = logits[i];
    const float ri = (float)rankings[i];   // ranks < 2^24: exact in f32

    const int jbase = bj * TILE;
    s_lj[tid] = logits[jbase + tid];
    s_rj[tid] = (float)rankings[jbase + tid];
    __syncthreads();

    const float LOG2E = 1.4426950408889634f;
    const float LN2   = 0.6931471805599453f;

    float acc = 0.0f;
    #pragma unroll 8
    for (int jj = 0; jj < TILE; ++jj) {
        const int   j  = jbase + jj;
        const float lj = s_lj[jj];   // same address all lanes -> LDS broadcast
        const float rj = s_rj[jj];
        const bool active = (j > i) && (rj > ri);
        const float d  = lj - li;
        const float ad = fabsf(d);
        // stable softplus: max(d,0) + ln2 * log2(1 + 2^(-|d|*log2e))
        const float sp = fmaxf(d, 0.0f)
                       + LN2 * __builtin_log2f(1.0f + __builtin_exp2f(-ad * LOG2E));
        const float w  = active ? __builtin_amdgcn_rcpf(ri + rj) : 0.0f;
        acc = fmaf(w, sp, acc);
    }

    // wave-level reduction (wave = 64 on CDNA)
    #pragma unroll
    for (int off = 32; off > 0; off >>= 1)
        acc += __shfl_down(acc, off, 64);

    const int wave = tid >> 6;
    if ((tid & 63) == 0) s_partial[wave] = acc;
    __syncthreads();

    if (tid == 0) {
        float s = 0.0f;
        #pragma unroll
        for (int w = 0; w < TILE / 64; ++w) s += s_partial[w];
        atomicAdd(out, s * (1.0f / (float)N_CAND));
    }
}

extern "C" void kernel_launch(void* const* d_in, const int* in_sizes, int n_in,
                              void* d_out, int out_size, void* d_ws, size_t ws_size,
                              hipStream_t stream)
{
    const float* logits   = (const float*)d_in[0];
    const int*   rankings = (const int*)  d_in[1];
    float*       out      = (float*)d_out;

    // d_out is re-poisoned (0xAA) before every timed launch; zero it on-stream.
    (void)hipMemsetAsync(out, 0, sizeof(float), stream);

    dim3 grid(N_CAND / TILE, N_CAND / TILE);
    ranknet_loss_kernel<<<grid, dim3(TILE), 0, stream>>>(logits, rankings, out);
}